// Round 1
// baseline (148.443 us; speedup 1.0000x reference)
//
#include <hip/hip_runtime.h>

// DETR-style post-process: softmax scores/labels + box scale + per-image greedy NMS.
// Outputs (flat f32, concatenated): scores[B*Q] | labels[B*Q] | boxes[B*Q*4] | keep[B*Q]

constexpr int kB  = 32;
constexpr int kQ  = 1024;
constexpr int kNC = 256;
constexpr int kBQ = kB * kQ;
constexpr float kIouThr = 0.5f;

// IoU > thr with numpy-identical op ordering (no FMA contraction).
__device__ __forceinline__ bool iou_gt(const float4& a, float aa,
                                       const float4& b, float ba) {
  float lx = fmaxf(a.x, b.x);
  float ly = fmaxf(a.y, b.y);
  float rx = fminf(a.z, b.z);
  float ry = fminf(a.w, b.w);
  float w  = fmaxf(__fsub_rn(rx, lx), 0.0f);
  float h  = fmaxf(__fsub_rn(ry, ly), 0.0f);
  float inter = __fmul_rn(w, h);
  float uni   = __fsub_rn(__fadd_rn(aa, ba), inter);
  float iou   = __fdiv_rn(inter, fmaxf(uni, 1e-9f));
  return iou > kIouThr;
}

// One wave (64 lanes) per (b,q): 256 logits -> softmax score/label; also box cxcywh->xyxy*scale.
__global__ void k_score_box(const float* __restrict__ logits,
                            const float* __restrict__ pboxes,
                            const int* __restrict__ ts,
                            float* __restrict__ out) {
  int gw   = (int)((blockIdx.x * blockDim.x + threadIdx.x) >> 6);
  int lane = (int)(threadIdx.x & 63);
  if (gw >= kBQ) return;

  // coalesced: lane l loads logits[gw*256 + 4l .. 4l+3]
  float4 v = reinterpret_cast<const float4*>(logits)[gw * (kNC / 4) + lane];

  // max over all 256 (softmax stabilizer)
  float m = fmaxf(fmaxf(v.x, v.y), fmaxf(v.z, v.w));
  for (int off = 32; off > 0; off >>= 1) m = fmaxf(m, __shfl_xor(m, off, 64));

  // foreground (first 255 classes) max + argmax, first-occurrence tie-break
  float fw = (lane == 63) ? -INFINITY : v.w;
  float fm = v.x; int fi = lane * 4;
  if (v.y > fm) { fm = v.y; fi = lane * 4 + 1; }
  if (v.z > fm) { fm = v.z; fi = lane * 4 + 2; }
  if (fw  > fm) { fm = fw;  fi = lane * 4 + 3; }
  for (int off = 32; off > 0; off >>= 1) {
    float om = __shfl_xor(fm, off, 64);
    int   oi = __shfl_xor(fi, off, 64);
    if (om > fm || (om == fm && oi < fi)) { fm = om; fi = oi; }
  }

  // sum exp over all 256
  float s = expf(v.x - m) + expf(v.y - m) + expf(v.z - m) + expf(v.w - m);
  for (int off = 32; off > 0; off >>= 1) s += __shfl_xor(s, off, 64);

  if (lane == 0) {
    out[gw]        = expf(fm - m) / s;   // score = softmax prob of best fg class
    out[kBQ + gw]  = (float)fi;          // label as f32

    // box: cxcywh -> xyxy, scaled by (img_w, img_h, img_w, img_h)
    float4 pb = reinterpret_cast<const float4*>(pboxes)[gw];
    int bi = gw >> 10;
    float ih = (float)ts[bi * 2 + 0];
    float iw = (float)ts[bi * 2 + 1];
    float hw = __fmul_rn(0.5f, pb.z);
    float hh = __fmul_rn(0.5f, pb.w);
    float x0 = __fmul_rn(__fsub_rn(pb.x, hw), iw);
    float y0 = __fmul_rn(__fsub_rn(pb.y, hh), ih);
    float x1 = __fmul_rn(__fadd_rn(pb.x, hw), iw);
    float y1 = __fmul_rn(__fadd_rn(pb.y, hh), ih);
    reinterpret_cast<float4*>(out + 2 * kBQ)[gw] = make_float4(x0, y0, x1, y1);
  }
}

// One block (1024 threads = 16 waves) per image: stable sort by score desc,
// then chunked greedy-NMS bitmask scan (exactly matches reference greedy semantics).
__global__ void __launch_bounds__(1024) k_nms(float* __restrict__ out) {
  __shared__ unsigned long long keys[kQ];      // 8 KB sort keys
  __shared__ float4 sbox[kQ];                  // 16 KB sorted boxes
  __shared__ float  sarea[kQ];                 // 4 KB areas
  __shared__ unsigned long long diag[kQ];      // 8 KB per-row within-chunk masks
  __shared__ unsigned long long remv[kQ / 64]; // suppression words (sorted order)
  __shared__ unsigned long long aliveW;        // alive rows of the chunk just scanned

  const int tid  = (int)threadIdx.x;
  const int b    = (int)blockIdx.x;
  const int lane = tid & 63;
  const int wv   = tid >> 6;

  // Key: descending by score (positive floats -> bit-monotonic), ascending idx tie-break
  float sc = out[b * kQ + tid];
  unsigned int sb = __float_as_uint(sc);
  keys[tid] = ((unsigned long long)(~sb) << 32) | (unsigned int)tid;
  if (tid < kQ / 64) remv[tid] = 0ull;
  __syncthreads();

  // bitonic sort ascending on u64 keys
  for (int k = 2; k <= kQ; k <<= 1) {
    for (int j = k >> 1; j > 0; j >>= 1) {
      int ixj = tid ^ j;
      if (ixj > tid) {
        unsigned long long a = keys[tid];
        unsigned long long c = keys[ixj];
        bool up = ((tid & k) == 0);
        if ((a > c) == up) { keys[tid] = c; keys[ixj] = a; }
      }
      __syncthreads();
    }
  }

  unsigned int oi = (unsigned int)(keys[tid] & 0xFFFFFFFFull);
  float4 bx = reinterpret_cast<const float4*>(out + 2 * kBQ)[b * kQ + (int)oi];
  sbox[tid]  = bx;
  float ar   = __fmul_rn(__fsub_rn(bx.z, bx.x), __fsub_rn(bx.w, bx.y));
  sarea[tid] = ar;
  __syncthreads();

  // diagonal 64x64 masks: row tid, bits jj>lane within own chunk (broadcast LDS reads)
  {
    int cbase = tid & ~63;
    unsigned long long w = 0ull;
    for (int jj = 0; jj < 64; ++jj) {
      if (jj > lane) {
        int j = cbase + jj;
        if (iou_gt(bx, ar, sbox[j], sarea[j])) w |= (1ull << jj);
      }
    }
    diag[tid] = w;
  }
  __syncthreads();

  bool supp = false;
  for (int c = 0; c < kQ / 64; ++c) {
    // wave 0: in-register serial greedy scan of chunk c over alive bits only
    if (tid < 64) {
      unsigned long long dw = diag[c * 64 + tid];
      unsigned int dlo = (unsigned int)dw;
      unsigned int dhi = (unsigned int)(dw >> 32);
      unsigned long long r = remv[c];       // uniform
      unsigned long long todo = ~r;
      while (todo) {
        int l = __builtin_ctzll(todo);      // lowest still-alive row
        unsigned int wlo = (unsigned int)__builtin_amdgcn_readlane((int)dlo, l);
        unsigned int whi = (unsigned int)__builtin_amdgcn_readlane((int)dhi, l);
        r |= ((unsigned long long)whi << 32) | (unsigned long long)wlo;
        todo &= ~r;
        todo &= ~(1ull << l);
      }
      if (tid == 0) { remv[c] = r; aliveW = ~r; }
    }
    __syncthreads();

    if (wv == c) {
      // pick up within-chunk suppression
      supp = supp || (((remv[c] >> lane) & 1ull) != 0ull);
    } else if (wv > c && !supp) {
      // cross-chunk: check only alive rows of chunk c
      unsigned long long alive = aliveW;
      while (alive) {
        int l = __builtin_ctzll(alive);
        alive &= alive - 1ull;
        int i = c * 64 + l;
        if (iou_gt(sbox[i], sarea[i], bx, ar)) { supp = true; break; }
      }
    }

    // reassemble suppression words from per-thread flags
    unsigned long long bal = __ballot(supp);
    if (lane == 0) remv[wv] = bal;
    __syncthreads();
  }

  // scatter keep back to original order
  out[6 * kBQ + b * kQ + (int)oi] = supp ? 0.0f : 1.0f;
}

extern "C" void kernel_launch(void* const* d_in, const int* in_sizes, int n_in,
                              void* d_out, int out_size, void* d_ws, size_t ws_size,
                              hipStream_t stream) {
  const float* logits = (const float*)d_in[0];
  const float* pboxes = (const float*)d_in[1];
  const int*   ts     = (const int*)d_in[2];
  float* out = (float*)d_out;

  // kernel 1: one wave per (b,q) -> 32768 waves, 4 waves/block
  dim3 g1(kBQ / 4), t1(256);
  k_score_box<<<g1, t1, 0, stream>>>(logits, pboxes, ts, out);

  // kernel 2: one block per image
  k_nms<<<kB, 1024, 0, stream>>>(out);
}

// Round 2
// 107.610 us; speedup vs baseline: 1.3795x; 1.3795x over previous
//
#include <hip/hip_runtime.h>

// DETR-style post-process: softmax scores/labels + box scale + per-image greedy NMS.
// Outputs (flat f32, concatenated): scores[B*Q] | labels[B*Q] | boxes[B*Q*4] | keep[B*Q]
//
// Pipeline:
//  k_score_box : per-(b,q) wave softmax/argmax + box conversion   (HBM-bound)
//  k_rank      : counting-rank (stable descending argsort) -> sorted boxes in ws
//  k_mask      : full suppression bitmask W[j][c] (column form), chip-wide parallel
//  k_scan      : per-image chunked greedy scan (only the true serial recurrence)

constexpr int kB  = 32;
constexpr int kQ  = 1024;
constexpr int kNC = 256;
constexpr int kBQ = kB * kQ;
constexpr float kIouThr = 0.5f;

typedef unsigned long long u64;
typedef unsigned int u32;

// IoU > thr with numpy-identical op ordering (no FMA contraction, exact division).
__device__ __forceinline__ bool iou_gt(const float4& a, float aa,
                                       const float4& b, float ba) {
  float lx = fmaxf(a.x, b.x);
  float ly = fmaxf(a.y, b.y);
  float rx = fminf(a.z, b.z);
  float ry = fminf(a.w, b.w);
  float w  = fmaxf(__fsub_rn(rx, lx), 0.0f);
  float h  = fmaxf(__fsub_rn(ry, ly), 0.0f);
  float inter = __fmul_rn(w, h);
  float uni   = __fsub_rn(__fadd_rn(aa, ba), inter);
  float iou   = __fdiv_rn(inter, fmaxf(uni, 1e-9f));
  return iou > kIouThr;
}

// One wave (64 lanes) per (b,q): 256 logits -> softmax score/label; box cxcywh->xyxy*scale.
__global__ void k_score_box(const float* __restrict__ logits,
                            const float* __restrict__ pboxes,
                            const int* __restrict__ ts,
                            float* __restrict__ out) {
  int gw   = (int)((blockIdx.x * blockDim.x + threadIdx.x) >> 6);
  int lane = (int)(threadIdx.x & 63);
  if (gw >= kBQ) return;

  float4 v = reinterpret_cast<const float4*>(logits)[gw * (kNC / 4) + lane];

  float m = fmaxf(fmaxf(v.x, v.y), fmaxf(v.z, v.w));
  for (int off = 32; off > 0; off >>= 1) m = fmaxf(m, __shfl_xor(m, off, 64));

  // foreground (first 255 classes) max + argmax, first-occurrence tie-break
  float fw = (lane == 63) ? -INFINITY : v.w;
  float fm = v.x; int fi = lane * 4;
  if (v.y > fm) { fm = v.y; fi = lane * 4 + 1; }
  if (v.z > fm) { fm = v.z; fi = lane * 4 + 2; }
  if (fw  > fm) { fm = fw;  fi = lane * 4 + 3; }
  for (int off = 32; off > 0; off >>= 1) {
    float om = __shfl_xor(fm, off, 64);
    int   oi = __shfl_xor(fi, off, 64);
    if (om > fm || (om == fm && oi < fi)) { fm = om; fi = oi; }
  }

  float s = expf(v.x - m) + expf(v.y - m) + expf(v.z - m) + expf(v.w - m);
  for (int off = 32; off > 0; off >>= 1) s += __shfl_xor(s, off, 64);

  if (lane == 0) {
    out[gw]        = expf(fm - m) / s;
    out[kBQ + gw]  = (float)fi;

    float4 pb = reinterpret_cast<const float4*>(pboxes)[gw];
    int bi = gw >> 10;
    float ih = (float)ts[bi * 2 + 0];
    float iw = (float)ts[bi * 2 + 1];
    float hw = __fmul_rn(0.5f, pb.z);
    float hh = __fmul_rn(0.5f, pb.w);
    float x0 = __fmul_rn(__fsub_rn(pb.x, hw), iw);
    float y0 = __fmul_rn(__fsub_rn(pb.y, hh), ih);
    float x1 = __fmul_rn(__fadd_rn(pb.x, hw), iw);
    float y1 = __fmul_rn(__fadd_rn(pb.y, hh), ih);
    reinterpret_cast<float4*>(out + 2 * kBQ)[gw] = make_float4(x0, y0, x1, y1);
  }
}

// Counting rank: rank_j = #{k : key_k < key_j}, key = (~score_bits)<<32 | idx.
// Exactly reproduces stable argsort(-scores). Scatters sorted boxes/areas/order to ws.
__global__ void __launch_bounds__(256) k_rank(const float* __restrict__ out,
                                              u32* __restrict__ order,
                                              float4* __restrict__ sbox,
                                              float* __restrict__ sarea) {
  __shared__ u64 keys[kQ];
  const int b = (int)blockIdx.x, sb = (int)blockIdx.y, tid = (int)threadIdx.x;

  for (int t = tid; t < kQ; t += 256) {
    u32 s = __float_as_uint(out[b * kQ + t]);       // scores > 0 -> bit-monotone
    keys[t] = ((u64)(~s) << 32) | (u32)t;
  }
  __syncthreads();

  const int j = sb * 256 + tid;
  const u64 kj = keys[j];
  int cnt = 0;
  #pragma unroll 4
  for (int k = 0; k < kQ; k += 2) {                 // broadcast LDS reads
    cnt += (int)(keys[k] < kj) + (int)(keys[k + 1] < kj);
  }

  float4 bx = reinterpret_cast<const float4*>(out + 2 * kBQ)[b * kQ + j];
  order[b * kQ + cnt] = (u32)j;
  sbox[b * kQ + cnt]  = bx;
  sarea[b * kQ + cnt] = __fmul_rn(__fsub_rn(bx.z, bx.x), __fsub_rn(bx.w, bx.y));
}

// Column-form suppression bitmask: maskT[b][c][j] bit l = (i=c*64+l < j) && IoU(i,j)>thr.
// Block (b, jb, cb): j in [jb*128, jb*128+128), i in [cb*256, cb*256+256) = chunks cb*4..cb*4+3.
__global__ void __launch_bounds__(128) k_mask(const float4* __restrict__ sbox,
                                              const float* __restrict__ sarea,
                                              u64* __restrict__ maskT) {
  const int b = (int)blockIdx.x, jb = (int)blockIdx.y, cb = (int)blockIdx.z;
  const int tid = (int)threadIdx.x;
  if (cb * 256 >= jb * 128 + 128) return;           // no i < j in this tile

  __shared__ float4 ibox[256];
  __shared__ float  iarea[256];
  for (int t = tid; t < 256; t += 128) {
    ibox[t]  = sbox[b * kQ + cb * 256 + t];
    iarea[t] = sarea[b * kQ + cb * 256 + t];
  }
  __syncthreads();

  const int j = jb * 128 + tid;
  const float4 bj = sbox[b * kQ + j];
  const float  aj = sarea[b * kQ + j];

  for (int c8 = 0; c8 < 4; ++c8) {
    const int c = cb * 4 + c8;
    u32 wlo = 0, whi = 0;
    #pragma unroll 4
    for (int l = 0; l < 64; ++l) {
      const int il = c8 * 64 + l;
      const int i  = cb * 256 + il;
      bool bit = (i < j) && iou_gt(ibox[il], iarea[il], bj, aj);
      if (l < 32) wlo |= ((u32)bit) << l;
      else        whi |= ((u32)bit) << (l - 32);
    }
    maskT[(b * 16 + c) * kQ + j] = ((u64)whi << 32) | wlo;
  }
}

// Per-image greedy scan. 16 waves; wave c owns sorted rows [c*64, c*64+64).
// Per chunk: wave c does the serial in-register greedy scan (candidate-skip),
// later waves fold with one AND against the alive set. One barrier per chunk.
__global__ void __launch_bounds__(1024) k_scan(const u64* __restrict__ maskT,
                                               const u32* __restrict__ order,
                                               float* __restrict__ out) {
  __shared__ u64 aliveS[16];
  const int b = (int)blockIdx.x, tid = (int)threadIdx.x;
  const int lane = tid & 63, wv = tid >> 6;

  bool supp = false;
  u64 wcur = maskT[(b * 16 + 0) * kQ + tid];        // chunk-0 word (prefetched)

  for (int c = 0; c < 16; ++c) {
    u64 wnext = (c < 15) ? maskT[(b * 16 + c + 1) * kQ + tid] : 0ull;

    if (wv == c) {
      u64 prior = __ballot(supp);                   // already-suppressed lanes
      u32 dlo = (u32)wcur, dhi = (u32)(wcur >> 32);
      u64 alive = 0ull;
      u64 todo = ~prior;                            // candidates, rank order
      while (todo) {
        int l = __builtin_ctzll(todo);
        todo &= todo - 1ull;
        u64 w = ((u64)(u32)__builtin_amdgcn_readlane((int)dhi, l) << 32)
              |  (u64)(u32)__builtin_amdgcn_readlane((int)dlo, l);
        if ((w & alive) == 0ull) alive |= 1ull << l;  // kept only if no alive overlap
      }
      if (lane == 0) aliveS[c] = alive;
      supp = ((alive >> lane) & 1ull) == 0ull;
    }
    __syncthreads();
    if (wv > c) supp = supp || ((wcur & aliveS[c]) != 0ull);
    wcur = wnext;
  }

  u32 oj = order[b * kQ + tid];
  out[6 * kBQ + b * kQ + (int)oj] = supp ? 0.0f : 1.0f;
}

extern "C" void kernel_launch(void* const* d_in, const int* in_sizes, int n_in,
                              void* d_out, int out_size, void* d_ws, size_t ws_size,
                              hipStream_t stream) {
  const float* logits = (const float*)d_in[0];
  const float* pboxes = (const float*)d_in[1];
  const int*   ts     = (const int*)d_in[2];
  float* out = (float*)d_out;

  // ws layout (≈4.75 MB): maskT | order | sbox | sarea
  char* ws = (char*)d_ws;
  u64*    maskT = (u64*)ws;                                   // 32*16*1024*8 = 4 MB
  u32*    order = (u32*)(ws + 4 * 1024 * 1024);               // 128 KB
  float4* sbox  = (float4*)(ws + 4 * 1024 * 1024 + 128 * 1024);   // 512 KB
  float*  sarea = (float*)(ws + 4 * 1024 * 1024 + 640 * 1024);    // 128 KB

  dim3 g1(kBQ / 4), t1(256);
  k_score_box<<<g1, t1, 0, stream>>>(logits, pboxes, ts, out);

  dim3 g2(kB, kQ / 256), t2(256);
  k_rank<<<g2, t2, 0, stream>>>(out, order, sbox, sarea);

  dim3 g3(kB, kQ / 128, 4), t3(128);
  k_mask<<<g3, t3, 0, stream>>>(sbox, sarea, maskT);

  k_scan<<<kB, 1024, 0, stream>>>(maskT, order, out);
}

// Round 3
// 92.809 us; speedup vs baseline: 1.5994x; 1.1595x over previous
//
#include <hip/hip_runtime.h>

// DETR-style post-process: softmax scores/labels + box scale + per-image greedy NMS.
// Outputs (flat f32, concatenated): scores[B*Q] | labels[B*Q] | boxes[B*Q*4] | keep[B*Q]
//
// Pipeline:
//  k_score_box : per-(b,q) wave softmax/argmax + box conversion   (HBM-bound)
//  k_rank      : counting-rank (stable descending argsort) -> sorted boxes in ws
//  k_mask      : suppression bitmask, one wave per 64x64 triangular tile (VALU-bound)
//  k_scan      : per-image chunked greedy scan (only the true serial recurrence)

constexpr int kB  = 32;
constexpr int kQ  = 1024;
constexpr int kNC = 256;
constexpr int kBQ = kB * kQ;
constexpr float kIouThr = 0.5f;

typedef unsigned long long u64;
typedef unsigned int u32;

// IoU > thr with numpy-identical op ordering (no FMA contraction, exact division).
__device__ __forceinline__ bool iou_gt(const float4& a, float aa,
                                       const float4& b, float ba) {
  float lx = fmaxf(a.x, b.x);
  float ly = fmaxf(a.y, b.y);
  float rx = fminf(a.z, b.z);
  float ry = fminf(a.w, b.w);
  float w  = fmaxf(__fsub_rn(rx, lx), 0.0f);
  float h  = fmaxf(__fsub_rn(ry, ly), 0.0f);
  float inter = __fmul_rn(w, h);
  float uni   = __fsub_rn(__fadd_rn(aa, ba), inter);
  float iou   = __fdiv_rn(inter, fmaxf(uni, 1e-9f));
  return iou > kIouThr;
}

// One wave (64 lanes) per (b,q): 256 logits -> softmax score/label; box cxcywh->xyxy*scale.
__global__ void k_score_box(const float* __restrict__ logits,
                            const float* __restrict__ pboxes,
                            const int* __restrict__ ts,
                            float* __restrict__ out) {
  int gw   = (int)((blockIdx.x * blockDim.x + threadIdx.x) >> 6);
  int lane = (int)(threadIdx.x & 63);
  if (gw >= kBQ) return;

  float4 v = reinterpret_cast<const float4*>(logits)[gw * (kNC / 4) + lane];

  float m = fmaxf(fmaxf(v.x, v.y), fmaxf(v.z, v.w));
  for (int off = 32; off > 0; off >>= 1) m = fmaxf(m, __shfl_xor(m, off, 64));

  // foreground (first 255 classes) max + argmax, first-occurrence tie-break
  float fw = (lane == 63) ? -INFINITY : v.w;
  float fm = v.x; int fi = lane * 4;
  if (v.y > fm) { fm = v.y; fi = lane * 4 + 1; }
  if (v.z > fm) { fm = v.z; fi = lane * 4 + 2; }
  if (fw  > fm) { fm = fw;  fi = lane * 4 + 3; }
  for (int off = 32; off > 0; off >>= 1) {
    float om = __shfl_xor(fm, off, 64);
    int   oi = __shfl_xor(fi, off, 64);
    if (om > fm || (om == fm && oi < fi)) { fm = om; fi = oi; }
  }

  float s = expf(v.x - m) + expf(v.y - m) + expf(v.z - m) + expf(v.w - m);
  for (int off = 32; off > 0; off >>= 1) s += __shfl_xor(s, off, 64);

  if (lane == 0) {
    out[gw]        = expf(fm - m) / s;
    out[kBQ + gw]  = (float)fi;

    float4 pb = reinterpret_cast<const float4*>(pboxes)[gw];
    int bi = gw >> 10;
    float ih = (float)ts[bi * 2 + 0];
    float iw = (float)ts[bi * 2 + 1];
    float hw = __fmul_rn(0.5f, pb.z);
    float hh = __fmul_rn(0.5f, pb.w);
    float x0 = __fmul_rn(__fsub_rn(pb.x, hw), iw);
    float y0 = __fmul_rn(__fsub_rn(pb.y, hh), ih);
    float x1 = __fmul_rn(__fadd_rn(pb.x, hw), iw);
    float y1 = __fmul_rn(__fadd_rn(pb.y, hh), ih);
    reinterpret_cast<float4*>(out + 2 * kBQ)[gw] = make_float4(x0, y0, x1, y1);
  }
}

// Counting rank: rank_j = #{k : key_k < key_j}, key = (~score_bits)<<32 | idx.
// Exactly reproduces stable argsort(-scores). Scatters sorted boxes/areas/order to ws.
__global__ void __launch_bounds__(256) k_rank(const float* __restrict__ out,
                                              u32* __restrict__ order,
                                              float4* __restrict__ sbox,
                                              float* __restrict__ sarea) {
  __shared__ u64 keys[kQ];
  const int b = (int)blockIdx.x, sb = (int)blockIdx.y, tid = (int)threadIdx.x;

  for (int t = tid; t < kQ; t += 256) {
    u32 s = __float_as_uint(out[b * kQ + t]);       // scores > 0 -> bit-monotone
    keys[t] = ((u64)(~s) << 32) | (u32)t;
  }
  __syncthreads();

  const int j = sb * 256 + tid;
  const u64 kj = keys[j];
  int cnt = 0;
  #pragma unroll 4
  for (int k = 0; k < kQ; k += 2) {                 // broadcast LDS reads
    cnt += (int)(keys[k] < kj) + (int)(keys[k + 1] < kj);
  }

  float4 bx = reinterpret_cast<const float4*>(out + 2 * kBQ)[b * kQ + j];
  order[b * kQ + cnt] = (u32)j;
  sbox[b * kQ + cnt]  = bx;
  sarea[b * kQ + cnt] = __fmul_rn(__fsub_rn(bx.z, bx.x), __fsub_rn(bx.w, bx.y));
}

// Suppression bitmask, column form: maskT[b][c][j] bit l = (i=c*64+l < j) && IoU(i,j)>thr.
// One wave per 64x64 tile: block (b, jb, c), active iff c <= jb. 4352 active waves.
__global__ void __launch_bounds__(64) k_mask(const float4* __restrict__ sbox,
                                             const float* __restrict__ sarea,
                                             u64* __restrict__ maskT) {
  const int b = (int)blockIdx.x, jb = (int)blockIdx.y, c = (int)blockIdx.z;
  if (c > jb) return;
  const int lane = (int)threadIdx.x;

  __shared__ float4 ibox[64];
  __shared__ float  iarea[64];
  ibox[lane]  = sbox[b * kQ + c * 64 + lane];
  iarea[lane] = sarea[b * kQ + c * 64 + lane];
  __syncthreads();

  const int j = jb * 64 + lane;
  const float4 bj = sbox[b * kQ + j];
  const float  aj = sarea[b * kQ + j];

  u32 wlo = 0, whi = 0;
  if (c < jb) {                                    // full tile: every i < j
    #pragma unroll 8
    for (int l = 0; l < 32; ++l)
      wlo |= ((u32)iou_gt(ibox[l], iarea[l], bj, aj)) << l;
    #pragma unroll 8
    for (int l = 0; l < 32; ++l)
      whi |= ((u32)iou_gt(ibox[l + 32], iarea[l + 32], bj, aj)) << l;
  } else {                                         // diagonal tile: strict l < lane
    #pragma unroll 8
    for (int l = 0; l < 32; ++l)
      wlo |= ((u32)((l < lane) && iou_gt(ibox[l], iarea[l], bj, aj))) << l;
    #pragma unroll 8
    for (int l = 0; l < 32; ++l)
      whi |= ((u32)((l + 32 < lane) && iou_gt(ibox[l + 32], iarea[l + 32], bj, aj))) << l;
  }
  maskT[(b * 16 + c) * kQ + j] = ((u64)whi << 32) | wlo;
}

// Per-image greedy scan. 16 waves; wave c owns sorted rows [c*64, c*64+64).
// Per chunk: wave c does the serial in-register greedy scan, later waves fold
// with one AND against the alive set. One barrier per chunk.
__global__ void __launch_bounds__(1024) k_scan(const u64* __restrict__ maskT,
                                               const u32* __restrict__ order,
                                               float* __restrict__ out) {
  __shared__ u64 aliveS[16];
  const int b = (int)blockIdx.x, tid = (int)threadIdx.x;
  const int lane = tid & 63, wv = tid >> 6;

  bool supp = false;
  u64 wcur = maskT[(b * 16 + 0) * kQ + tid];        // chunk-0 word (prefetched)

  for (int c = 0; c < 16; ++c) {
    u64 wnext = (c < 15) ? maskT[(b * 16 + c + 1) * kQ + tid] : 0ull;

    if (wv == c) {
      u64 prior = __ballot(supp);                   // already-suppressed lanes
      u32 dlo = (u32)wcur, dhi = (u32)(wcur >> 32);
      u64 alive = 0ull;
      u64 todo = ~prior;                            // candidates, rank order
      while (todo) {
        int l = __builtin_ctzll(todo);
        todo &= todo - 1ull;
        u64 w = ((u64)(u32)__builtin_amdgcn_readlane((int)dhi, l) << 32)
              |  (u64)(u32)__builtin_amdgcn_readlane((int)dlo, l);
        if ((w & alive) == 0ull) alive |= 1ull << l;  // kept only if no alive overlap
      }
      if (lane == 0) aliveS[c] = alive;
      supp = ((alive >> lane) & 1ull) == 0ull;
    }
    __syncthreads();
    if (wv > c) supp = supp || ((wcur & aliveS[c]) != 0ull);
    wcur = wnext;
  }

  u32 oj = order[b * kQ + tid];
  out[6 * kBQ + b * kQ + (int)oj] = supp ? 0.0f : 1.0f;
}

extern "C" void kernel_launch(void* const* d_in, const int* in_sizes, int n_in,
                              void* d_out, int out_size, void* d_ws, size_t ws_size,
                              hipStream_t stream) {
  const float* logits = (const float*)d_in[0];
  const float* pboxes = (const float*)d_in[1];
  const int*   ts     = (const int*)d_in[2];
  float* out = (float*)d_out;

  // ws layout (≈4.75 MB): maskT | order | sbox | sarea
  char* ws = (char*)d_ws;
  u64*    maskT = (u64*)ws;                                   // 32*16*1024*8 = 4 MB
  u32*    order = (u32*)(ws + 4 * 1024 * 1024);               // 128 KB
  float4* sbox  = (float4*)(ws + 4 * 1024 * 1024 + 128 * 1024);   // 512 KB
  float*  sarea = (float*)(ws + 4 * 1024 * 1024 + 640 * 1024);    // 128 KB

  dim3 g1(kBQ / 4), t1(256);
  k_score_box<<<g1, t1, 0, stream>>>(logits, pboxes, ts, out);

  dim3 g2(kB, kQ / 256), t2(256);
  k_rank<<<g2, t2, 0, stream>>>(out, order, sbox, sarea);

  dim3 g3(kB, 16, 16), t3(64);
  k_mask<<<g3, t3, 0, stream>>>(sbox, sarea, maskT);

  k_scan<<<kB, 1024, 0, stream>>>(maskT, order, out);
}